// Round 5
// baseline (605.457 us; speedup 1.0000x reference)
//
#include <hip/hip_runtime.h>
#include <math.h>

#define N_NODES 50000
#define N_EDGES 400000
#define LDH 136

typedef _Float16 half8 __attribute__((ext_vector_type(8)));
typedef float f32x4 __attribute__((ext_vector_type(4)));

// workspace layout (bytes)
#define AGG_OFF 0           // 50000*64 f32
#define XH_OFF  12800000    // 50000*64 f16
#define UH_OFF  19200000    // 64*16 f16
#define WP_OFF  19202048    // packed weights, 200704 f16
// packed-weight offsets (f16 elements)
#define O_EW1 0
#define O_EH0 28672
#define O_EH1 45056
#define O_EWO 61440
#define O_AW1 69632
#define O_AH0 98304
#define O_AH1 114688
#define O_AWO 131072
#define O_NW1 139264
#define O_NH0 159744
#define O_NH1 176128
#define O_NWO 192512

__device__ __forceinline__ f32x4 mfma16(half8 a, half8 b, f32x4 c) {
  return __builtin_amdgcn_mfma_f32_16x16x32_f16(a, b, c, 0, 0, 0);
}

__device__ __forceinline__ half8 cvt8(float4 a, float4 b) {
  half8 v;
  v[0] = (_Float16)a.x; v[1] = (_Float16)a.y; v[2] = (_Float16)a.z; v[3] = (_Float16)a.w;
  v[4] = (_Float16)b.x; v[5] = (_Float16)b.y; v[6] = (_Float16)b.z; v[7] = (_Float16)b.w;
  return v;
}

__device__ __forceinline__ half8 zero8() {
  half8 v;
#pragma unroll
  for (int j = 0; j < 8; ++j) v[j] = (_Float16)0.f;
  return v;
}

// ---------------------------------------------------------------------------
// Hidden layer slice: dst[0:64][w*32 .. +32) = relu(src[0:64][0:NS*32] @ W + b)
// B-fragments preloaded and PINNED above the MFMA loop via sched_barrier(0)
// so the NS*2 L2 loads overlap into a single latency exposure.
// ---------------------------------------------------------------------------
template<int NS>
__device__ __forceinline__ void gemm_h(const _Float16* __restrict__ src,
                                       _Float16* __restrict__ dst,
                                       const half8* __restrict__ wp,
                                       const float* __restrict__ bias,
                                       int w, int lane) {
  const int r = lane & 15, ch = lane >> 4;
  half8 B0[NS], B1[NS];
#pragma unroll
  for (int s = 0; s < NS; ++s) {
    B0[s] = wp[(s * 4 + ch) * 128 + w * 32 + r];
    B1[s] = wp[(s * 4 + ch) * 128 + w * 32 + 16 + r];
  }
  __builtin_amdgcn_sched_barrier(0);
  f32x4 a0[4], a1[4];
#pragma unroll
  for (int m = 0; m < 4; ++m) {
    a0[m] = (f32x4){0.f, 0.f, 0.f, 0.f};
    a1[m] = (f32x4){0.f, 0.f, 0.f, 0.f};
  }
#pragma unroll
  for (int s = 0; s < NS; ++s) {
#pragma unroll
    for (int m = 0; m < 4; ++m) {
      half8 a = *(const half8*)(src + (m * 16 + r) * LDH + s * 32 + ch * 8);
      a0[m] = mfma16(a, B0[s], a0[m]);
      a1[m] = mfma16(a, B1[s], a1[m]);
    }
  }
  float bb0 = bias[w * 32 + r], bb1 = bias[w * 32 + 16 + r];
#pragma unroll
  for (int m = 0; m < 4; ++m)
#pragma unroll
    for (int q = 0; q < 4; ++q) {
      int row = m * 16 + ch * 4 + q;
      dst[row * LDH + w * 32 + r]      = (_Float16)fmaxf(a0[m][q] + bb0, 0.f);
      dst[row * LDH + w * 32 + 16 + r] = (_Float16)fmaxf(a1[m][q] + bb1, 0.f);
    }
}

// ---------------------------------------------------------------------------
// Edge layer-1: A-fragments gathered per-lane straight from global (the gather
// IS the fragment load; no LDS staging). K = 208 padded to 224 (NS=7).
// ---------------------------------------------------------------------------
__device__ __forceinline__ void l1_edge(const _Float16* __restrict__ x_h,
                                        const float* __restrict__ edge_attr,
                                        const _Float16* __restrict__ u_h,
                                        const half8* __restrict__ wp,
                                        const float* __restrict__ bias,
                                        _Float16* __restrict__ dst,
                                        const int* srcm, const int* tgtm, const int* ebm,
                                        int e0, int w, int lane) {
  const int r = lane & 15, ch = lane >> 4;
  half8 B0[7], B1[7];
#pragma unroll
  for (int s = 0; s < 7; ++s) {
    B0[s] = wp[(s * 4 + ch) * 128 + w * 32 + r];
    B1[s] = wp[(s * 4 + ch) * 128 + w * 32 + 16 + r];
  }
  __builtin_amdgcn_sched_barrier(0);
  float bb0 = bias[w * 32 + r], bb1 = bias[w * 32 + 16 + r];
#pragma unroll
  for (int g = 0; g < 2; ++g) {
    half8 A[2][7];
#pragma unroll
    for (int mm = 0; mm < 2; ++mm) {
      int m = g * 2 + mm;
      const _Float16* xs = x_h + (size_t)srcm[m] * 64 + ch * 8;
      const _Float16* xt = x_h + (size_t)tgtm[m] * 64 + ch * 8;
      A[mm][0] = *(const half8*)(xs);
      A[mm][1] = *(const half8*)(xs + 32);
      A[mm][2] = *(const half8*)(xt);
      A[mm][3] = *(const half8*)(xt + 32);
      const float* ea = edge_attr + (size_t)(e0 + m * 16 + r) * 64 + ch * 8;
      float4 f0 = *(const float4*)(ea);
      float4 f1 = *(const float4*)(ea + 4);
      float4 f2 = *(const float4*)(ea + 32);
      float4 f3 = *(const float4*)(ea + 36);
      A[mm][4] = cvt8(f0, f1);
      A[mm][5] = cvt8(f2, f3);
      half8 vu = zero8();
      if (ch < 2) vu = *(const half8*)(u_h + ebm[m] * 16 + ch * 8);
      A[mm][6] = vu;
    }
    __builtin_amdgcn_sched_barrier(0);
    f32x4 a0[2], a1[2];
#pragma unroll
    for (int mm = 0; mm < 2; ++mm) {
      a0[mm] = (f32x4){0.f, 0.f, 0.f, 0.f};
      a1[mm] = (f32x4){0.f, 0.f, 0.f, 0.f};
    }
#pragma unroll
    for (int s = 0; s < 7; ++s)
#pragma unroll
      for (int mm = 0; mm < 2; ++mm) {
        a0[mm] = mfma16(A[mm][s], B0[s], a0[mm]);
        a1[mm] = mfma16(A[mm][s], B1[s], a1[mm]);
      }
#pragma unroll
    for (int mm = 0; mm < 2; ++mm)
#pragma unroll
      for (int q = 0; q < 4; ++q) {
        int row = (g * 2 + mm) * 16 + ch * 4 + q;
        dst[row * LDH + w * 32 + r]      = (_Float16)fmaxf(a0[mm][q] + bb0, 0.f);
        dst[row * LDH + w * 32 + 16 + r] = (_Float16)fmaxf(a1[mm][q] + bb1, 0.f);
      }
  }
}

// ---------------------------------------------------------------------------
// Output GEMM (64-wide) into acc[4] (each lane: 4 feats x 4 rows), + bias.
// ---------------------------------------------------------------------------
__device__ __forceinline__ void out_gemm(const _Float16* __restrict__ src,
                                         const half8* __restrict__ wpo,
                                         const float* __restrict__ bo,
                                         f32x4 acc[4], int w, int lane) {
  const int r = lane & 15, ch = lane >> 4;
  half8 BO[4][4];
#pragma unroll
  for (int s = 0; s < 4; ++s)
#pragma unroll
    for (int t = 0; t < 4; ++t) BO[s][t] = wpo[(s * 4 + ch) * 64 + t * 16 + r];
  __builtin_amdgcn_sched_barrier(0);
#pragma unroll
  for (int t = 0; t < 4; ++t) acc[t] = (f32x4){0.f, 0.f, 0.f, 0.f};
#pragma unroll
  for (int s = 0; s < 4; ++s) {
    half8 a = *(const half8*)(src + (w * 16 + r) * LDH + s * 32 + ch * 8);
#pragma unroll
    for (int t = 0; t < 4; ++t) acc[t] = mfma16(a, BO[s][t], acc[t]);
  }
#pragma unroll
  for (int t = 0; t < 4; ++t) {
    float bv = bo[t * 16 + r];
#pragma unroll
    for (int q = 0; q < 4; ++q) acc[t][q] += bv;
  }
}

// ---------------------------------------------------------------------------
struct EdgeP {
  const float* edge_attr; const int* edge_index; const int* batch;
  const _Float16* x_h; const _Float16* u_h; const _Float16* wp;
  const float *eBin, *eBh, *eBout, *eG, *eBt;
  const float *aBin, *aBh, *aBout, *aG, *aBt;
  float* agg;
};

// 64 edges/block, 256 threads (4 waves). e-path then a-path sequentially.
// LDS = 3 x 17408 = 52224 B -> 3 independent blocks/CU (12 waves/CU,
// decorrelated barriers). bufE (f32, ld=68) aliases sB.
__global__ __launch_bounds__(256, 3) void edge_kernel(EdgeP p) {
  __shared__ __align__(16) _Float16 sA[64 * LDH];
  __shared__ __align__(16) _Float16 sB[64 * LDH];
  __shared__ __align__(16) _Float16 sC[64 * LDH];
  const int tid = threadIdx.x, lane = tid & 63, w = tid >> 6;
  const int r = lane & 15, ch = lane >> 4;
  const int e0 = blockIdx.x * 64;

  int srcm[4], tgtm[4], ebm[4];
#pragma unroll
  for (int m = 0; m < 4; ++m) srcm[m] = p.edge_index[e0 + m * 16 + r];
#pragma unroll
  for (int m = 0; m < 4; ++m) tgtm[m] = p.edge_index[N_EDGES + e0 + m * 16 + r];
#pragma unroll
  for (int m = 0; m < 4; ++m) ebm[m] = p.batch[srcm[m]];

  // ---- e-path ----
  l1_edge(p.x_h, p.edge_attr, p.u_h, (const half8*)(p.wp + O_EW1), p.eBin, sA,
          srcm, tgtm, ebm, e0, w, lane);
  __syncthreads();
  gemm_h<4>(sA, sB, (const half8*)(p.wp + O_EH0), p.eBh, w, lane);       __syncthreads();
  gemm_h<4>(sB, sA, (const half8*)(p.wp + O_EH1), p.eBh + 128, w, lane); __syncthreads();

  float* bufE = (float*)sB;  // 64 x 68 f32 = 17408 B, exact alias
  {
    f32x4 acc[4];
    out_gemm(sA, (const half8*)(p.wp + O_EWO), p.eBout, acc, w, lane);
    float g4[4], b4[4];
#pragma unroll
    for (int t = 0; t < 4; ++t) { g4[t] = p.eG[t * 16 + r]; b4[t] = p.eBt[t * 16 + r]; }
#pragma unroll
    for (int q = 0; q < 4; ++q) {
      float s1 = 0.f, s2 = 0.f;
#pragma unroll
      for (int t = 0; t < 4; ++t) { float v = acc[t][q]; s1 += v; s2 += v * v; }
#pragma unroll
      for (int mk = 1; mk < 16; mk <<= 1) { s1 += __shfl_xor(s1, mk); s2 += __shfl_xor(s2, mk); }
      float mu = s1 * (1.f / 64);
      float rs = rsqrtf(s2 * (1.f / 64) - mu * mu + 1e-5f);
      int row = w * 16 + ch * 4 + q;
#pragma unroll
      for (int t = 0; t < 4; ++t)
        bufE[row * 68 + t * 16 + r] = (acc[t][q] - mu) * rs * g4[t] + b4[t];
    }
  }
  __syncthreads();

  // ---- a-path ----
  l1_edge(p.x_h, p.edge_attr, p.u_h, (const half8*)(p.wp + O_AW1), p.aBin, sC,
          srcm, tgtm, ebm, e0, w, lane);
  __syncthreads();
  gemm_h<4>(sC, sA, (const half8*)(p.wp + O_AH0), p.aBh, w, lane);       __syncthreads();
  gemm_h<4>(sA, sC, (const half8*)(p.wp + O_AH1), p.aBh + 128, w, lane); __syncthreads();

  {
    f32x4 acc[4];
    out_gemm(sC, (const half8*)(p.wp + O_AWO), p.aBout, acc, w, lane);
    float g4[4], b4[4];
#pragma unroll
    for (int t = 0; t < 4; ++t) { g4[t] = p.aG[t * 16 + r]; b4[t] = p.aBt[t * 16 + r]; }
    int tq[4];
#pragma unroll
    for (int q = 0; q < 4; ++q)
      tq[q] = p.edge_index[N_EDGES + e0 + w * 16 + ch * 4 + q];
#pragma unroll
    for (int q = 0; q < 4; ++q) {
      float s1 = 0.f, s2 = 0.f;
#pragma unroll
      for (int t = 0; t < 4; ++t) { float v = acc[t][q]; s1 += v; s2 += v * v; }
#pragma unroll
      for (int mk = 1; mk < 16; mk <<= 1) { s1 += __shfl_xor(s1, mk); s2 += __shfl_xor(s2, mk); }
      float mu = s1 * (1.f / 64);
      float rs = rsqrtf(s2 * (1.f / 64) - mu * mu + 1e-5f);
      int row = w * 16 + ch * 4 + q;
      float* ap = p.agg + (size_t)tq[q] * 64 + r;
#pragma unroll
      for (int t = 0; t < 4; ++t) {
        float oa = (acc[t][q] - mu) * rs * g4[t] + b4[t];
        float sg = 1.f / (1.f + __expf(-oa));
        atomicAdd(ap + t * 16, bufE[row * 68 + t * 16 + r] * sg);
      }
    }
  }
}

// ---------------------------------------------------------------------------
struct NodeP {
  const float* agg; const _Float16* x_h; const _Float16* u_h;
  const _Float16* wp; const int* batch;
  const float *Bin, *Bh, *Bout, *G, *Bt;
  float* out;
};

// Node layer-1 gather: K = 144 padded to 160 (NS=5).
__device__ __forceinline__ void l1_node(const NodeP& p,
                                        _Float16* __restrict__ dst,
                                        int n0, int w, int lane) {
  const int r = lane & 15, ch = lane >> 4;
  const half8* wp = (const half8*)(p.wp + O_NW1);
  half8 B0[5], B1[5];
#pragma unroll
  for (int s = 0; s < 5; ++s) {
    B0[s] = wp[(s * 4 + ch) * 128 + w * 32 + r];
    B1[s] = wp[(s * 4 + ch) * 128 + w * 32 + 16 + r];
  }
  __builtin_amdgcn_sched_barrier(0);
  float bb0 = p.Bin[w * 32 + r], bb1 = p.Bin[w * 32 + 16 + r];
#pragma unroll
  for (int g = 0; g < 2; ++g) {
    half8 A[2][5];
#pragma unroll
    for (int mm = 0; mm < 2; ++mm) {
      int m = g * 2 + mm;
      int n = n0 + m * 16 + r;
      int nn = (n < N_NODES) ? n : 0;
      const _Float16* xs = p.x_h + (size_t)nn * 64 + ch * 8;
      A[mm][0] = *(const half8*)(xs);
      A[mm][1] = *(const half8*)(xs + 32);
      const float* ag = p.agg + (size_t)nn * 64 + ch * 8;
      float4 f0 = *(const float4*)(ag);
      float4 f1 = *(const float4*)(ag + 4);
      float4 f2 = *(const float4*)(ag + 32);
      float4 f3 = *(const float4*)(ag + 36);
      A[mm][2] = cvt8(f0, f1);
      A[mm][3] = cvt8(f2, f3);
      half8 vu = zero8();
      if (ch < 2) vu = *(const half8*)(p.u_h + p.batch[nn] * 16 + ch * 8);
      A[mm][4] = vu;
    }
    __builtin_amdgcn_sched_barrier(0);
    f32x4 a0[2], a1[2];
#pragma unroll
    for (int mm = 0; mm < 2; ++mm) {
      a0[mm] = (f32x4){0.f, 0.f, 0.f, 0.f};
      a1[mm] = (f32x4){0.f, 0.f, 0.f, 0.f};
    }
#pragma unroll
    for (int s = 0; s < 5; ++s)
#pragma unroll
      for (int mm = 0; mm < 2; ++mm) {
        a0[mm] = mfma16(A[mm][s], B0[s], a0[mm]);
        a1[mm] = mfma16(A[mm][s], B1[s], a1[mm]);
      }
#pragma unroll
    for (int mm = 0; mm < 2; ++mm)
#pragma unroll
      for (int q = 0; q < 4; ++q) {
        int row = (g * 2 + mm) * 16 + ch * 4 + q;
        dst[row * LDH + w * 32 + r]      = (_Float16)fmaxf(a0[mm][q] + bb0, 0.f);
        dst[row * LDH + w * 32 + 16 + r] = (_Float16)fmaxf(a1[mm][q] + bb1, 0.f);
      }
  }
}

// 64 nodes/block, 256 threads. LDS = 2 x 17408 = 34816 -> 4 blocks/CU.
__global__ __launch_bounds__(256, 4) void node_kernel(NodeP p) {
  __shared__ __align__(16) _Float16 sQ[64 * LDH];
  __shared__ __align__(16) _Float16 sP[64 * LDH];
  const int tid = threadIdx.x, lane = tid & 63, w = tid >> 6;
  const int r = lane & 15, ch = lane >> 4;
  const int n0 = blockIdx.x * 64;

  l1_node(p, sQ, n0, w, lane);
  __syncthreads();
  gemm_h<4>(sQ, sP, (const half8*)(p.wp + O_NH0), p.Bh, w, lane);       __syncthreads();
  gemm_h<4>(sP, sQ, (const half8*)(p.wp + O_NH1), p.Bh + 128, w, lane); __syncthreads();

  f32x4 acc[4];
  out_gemm(sQ, (const half8*)(p.wp + O_NWO), p.Bout, acc, w, lane);
  float g4[4], b4[4];
#pragma unroll
  for (int t = 0; t < 4; ++t) { g4[t] = p.G[t * 16 + r]; b4[t] = p.Bt[t * 16 + r]; }
#pragma unroll
  for (int q = 0; q < 4; ++q) {
    float s1 = 0.f, s2 = 0.f;
#pragma unroll
    for (int t = 0; t < 4; ++t) { float v = acc[t][q]; s1 += v; s2 += v * v; }
#pragma unroll
    for (int mk = 1; mk < 16; mk <<= 1) { s1 += __shfl_xor(s1, mk); s2 += __shfl_xor(s2, mk); }
    float mu = s1 * (1.f / 64);
    float rs = rsqrtf(s2 * (1.f / 64) - mu * mu + 1e-5f);
    int row = w * 16 + ch * 4 + q;
    int n = n0 + row;
    if (n < N_NODES) {
#pragma unroll
      for (int t = 0; t < 4; ++t)
        p.out[(size_t)n * 64 + t * 16 + r] = (acc[t][q] - mu) * rs * g4[t] + b4[t];
    }
  }
}

// ---------------------------------------------------------------------------
// Per-call pack: fp32 weights -> MFMA-B-fragment-packed fp16; x,u -> fp16.
// wdst[((s*4+c)*N + n)*8 + j] = W[s*32+c*8+j][n]  (0 if k >= Kreal)
// ---------------------------------------------------------------------------
#define GX 112
struct PackP {
  const float* src[12];
  int Kreal[12], Nlog[12], size[12], dstoff[12];
  const float* x; const float* u;
  _Float16* x_h; _Float16* u_h; _Float16* wdst;
};

__global__ void pack_kernel(PackP p) {
  int y = blockIdx.y;
  int idx = blockIdx.x * 256 + threadIdx.x;
  if (y < 12) {
    int sz = p.size[y];
    if (idx >= sz) return;
    int N = 1 << p.Nlog[y];
    int j = idx & 7, t = idx >> 3;
    int n = t & (N - 1);
    int sc = t >> p.Nlog[y];
    int c = sc & 3, s = sc >> 2;
    int k = s * 32 + c * 8 + j;
    p.wdst[p.dstoff[y] + idx] =
        (k < p.Kreal[y]) ? (_Float16)p.src[y][k * N + n] : (_Float16)0.f;
  } else {
    for (int i = idx; i < N_NODES * 64; i += GX * 256) p.x_h[i] = (_Float16)p.x[i];
    for (int i = idx; i < 64 * 16; i += GX * 256) p.u_h[i] = (_Float16)p.u[i];
  }
}

// ---------------------------------------------------------------------------
extern "C" void kernel_launch(void* const* d_in, const int* in_sizes, int n_in,
                              void* d_out, int out_size, void* d_ws, size_t ws_size,
                              hipStream_t stream) {
  const float* x = (const float*)d_in[0];
  const float* edge_attr = (const float*)d_in[1];
  const float* u = (const float*)d_in[2];
  const int* edge_index = (const int*)d_in[3];
  const int* batch = (const int*)d_in[4];

  char* ws = (char*)d_ws;
  float* agg = (float*)(ws + AGG_OFF);
  _Float16* x_h = (_Float16*)(ws + XH_OFF);
  _Float16* u_h = (_Float16*)(ws + UH_OFF);
  _Float16* wp = (_Float16*)(ws + WP_OFF);

  hipMemsetAsync(agg, 0, (size_t)N_NODES * 64 * sizeof(float), stream);

  PackP pk;
  const float* eWh = (const float*)d_in[7];
  const float* aWh = (const float*)d_in[15];
  const float* nWh = (const float*)d_in[23];
  const float* srcs[12] = {
      (const float*)d_in[5], eWh, eWh + 16384, (const float*)d_in[9],
      (const float*)d_in[13], aWh, aWh + 16384, (const float*)d_in[17],
      (const float*)d_in[21], nWh, nWh + 16384, (const float*)d_in[25]};
  const int kr[12] = {208, 128, 128, 128, 208, 128, 128, 128, 144, 128, 128, 128};
  const int nl[12] = {7, 7, 7, 6, 7, 7, 7, 6, 7, 7, 7, 6};
  const int sz[12] = {28672, 16384, 16384, 8192, 28672, 16384, 16384, 8192,
                      20480, 16384, 16384, 8192};
  const int off[12] = {O_EW1, O_EH0, O_EH1, O_EWO, O_AW1, O_AH0, O_AH1, O_AWO,
                       O_NW1, O_NH0, O_NH1, O_NWO};
  for (int i = 0; i < 12; ++i) {
    pk.src[i] = srcs[i]; pk.Kreal[i] = kr[i]; pk.Nlog[i] = nl[i];
    pk.size[i] = sz[i]; pk.dstoff[i] = off[i];
  }
  pk.x = x; pk.u = u; pk.x_h = x_h; pk.u_h = u_h; pk.wdst = wp;
  pack_kernel<<<dim3(GX, 13), 256, 0, stream>>>(pk);

  EdgeP ep;
  ep.edge_attr = edge_attr; ep.edge_index = edge_index; ep.batch = batch;
  ep.x_h = x_h; ep.u_h = u_h; ep.wp = wp;
  ep.eBin = (const float*)d_in[6];  ep.eBh = (const float*)d_in[8];
  ep.eBout = (const float*)d_in[10]; ep.eG = (const float*)d_in[11];
  ep.eBt = (const float*)d_in[12];
  ep.aBin = (const float*)d_in[14]; ep.aBh = (const float*)d_in[16];
  ep.aBout = (const float*)d_in[18]; ep.aG = (const float*)d_in[19];
  ep.aBt = (const float*)d_in[20];
  ep.agg = agg;
  edge_kernel<<<N_EDGES / 64, 256, 0, stream>>>(ep);

  NodeP np;
  np.agg = agg; np.x_h = x_h; np.u_h = u_h; np.wp = wp; np.batch = batch;
  np.Bin = (const float*)d_in[22]; np.Bh = (const float*)d_in[24];
  np.Bout = (const float*)d_in[26]; np.G = (const float*)d_in[27];
  np.Bt = (const float*)d_in[28];
  np.out = (float*)d_out;
  node_kernel<<<(N_NODES + 63) / 64, 256, 0, stream>>>(np);
}